// Round 13
// baseline (97.425 us; speedup 1.0000x reference)
//
#include <hip/hip_runtime.h>
#include <hip/hip_bf16.h>
#include <math.h>

// Shapes: B=32, C=128, O=128, K=3, L=4096, W=1, PAD=1, DIL=1
// Fully fused (r13): one kernel per (128-i tile, b), 45.5 KB LDS (3 blocks/CU).
//   pass A: 4 x {stage win[32c x 160i] from HBM -> 3 conv MFMAs} -> conv C-frag
//   exchange: cv -> convx (aliased on Bl) -> per-lane gather params (registers)
//   pass B: r12 phase loop verbatim; win re-staged from L2 (x is cache-warm).
// x read from HBM once; no param round-trip; pass A/B of different blocks
// overlap on a CU (the TLP the standalone prep kernel lacked).
//
// ws layout (bytes):
//   WrA @ 0     : bf16 A-frags main GEMM, 8m x 12s x 64 x 16B = 98304
//   WcA @ 98304 : bf16 A-frags conv, 12s x 64 x 16B = 12288

typedef __attribute__((ext_vector_type(8))) short bf16x8;
typedef __attribute__((ext_vector_type(4))) float f32x4;
typedef float f32x2u __attribute__((ext_vector_type(2), aligned(4)));

#define WIN 160
#define WPAD 161

static __device__ inline unsigned short f2bf(float f) {
    __hip_bfloat16 h = __float2bfloat16(f);
    union { __hip_bfloat16 b; unsigned short u; } cv;
    cv.b = h;
    return cv.u;
}

// ---------- kernel 0: pack WrA (main A-frags) + WcA (conv A-frags) ----------
// A-frag (m,s), lane l, elem e:  A[o = m*16+(l&15)][kc = s*32+(l>>4)*8+e]
// kc = tap*128 + c  (s = tap*4 + cblock for conv)
__global__ __launch_bounds__(256) void k_wra(const float* __restrict__ w_reg,
                                             const float* __restrict__ w_off,
                                             const float* __restrict__ w_mod,
                                             unsigned short* __restrict__ WrA,
                                             unsigned short* __restrict__ WcA) {
    int t = blockIdx.x * 256 + threadIdx.x;
    if (t < 49152) {
        int e  = t & 7;
        int l  = (t >> 3) & 63;
        int ms = t >> 9;              // m*12 + s
        int m  = ms / 12;
        int s  = ms - m * 12;
        int o  = m * 16 + (l & 15);
        int kc = s * 32 + ((l >> 4) & 3) * 8 + e;
        int tap = kc >> 7;
        int c   = kc & 127;
        WrA[t] = f2bf(w_reg[(o * 128 + c) * 3 + tap]);
    } else if (t < 49152 + 6144) {
        int u = t - 49152;
        int e = u & 7;
        int l = (u >> 3) & 63;
        int s = u >> 9;               // 0..11 = tap*4 + cblock
        int o = l & 15;
        int c   = (s & 3) * 32 + ((l >> 4) & 3) * 8 + e;
        int tap = s >> 2;
        float v = 0.f;
        if (o < 6)      v = w_off[(o * 128 + c) * 3 + tap];
        else if (o < 9) v = w_mod[((o - 6) * 128 + c) * 3 + tap];
        WcA[u] = f2bf(v);
    }
}

// ---------- kernel 1: fully fused conv + gather + GEMM ----------
// grid (32 i-tiles, 32 b), 512 threads = 8 waves. Block: 128 i x 128 o.
__global__ __launch_bounds__(512) void k_all(const unsigned short* __restrict__ WrA,
                                             const unsigned short* __restrict__ WcA,
                                             const float* __restrict__ x,
                                             const float* __restrict__ b_off,
                                             const float* __restrict__ b_mod,
                                             float* __restrict__ out) {
    __shared__ float win[32 * WPAD];               // 20.6 KB, staged per phase
    __shared__ short Bl[8][3][512];                // 24 KB single-buffered B-frags
    float* convx = (float*)&Bl[0][0][0];           // [9][132] aliased scratch

    int t = threadIdx.x;
    int l = t & 63;
    int w = t >> 6;                                // 0..7
    int b  = blockIdx.y;
    int ib = blockIdx.x;
    int q  = l >> 4;
    int il = l & 15;
    int i0t = ib * 128;
    int wsod = i0t - 16;
    if (wsod > 4096 - WIN) wsod = 4096 - WIN;
    if (wsod < 0) wsod = 0;
    const float* xb = x + (size_t)b * 524288;
    const bf16x8* Ag = (const bf16x8*)WrA;
    const bf16x8* Ac = (const bf16x8*)WcA;
    int gi = i0t + w * 16 + il;                    // producer/conv i for this lane

    // ---- pass A: conv via MFMA over 4 window phases (stage from HBM) ----
    f32x4 cv = (f32x4){0.f, 0.f, 0.f, 0.f};
    for (int cc = 0; cc < 4; ++cc) {
        int cb = cc * 32;
        __syncthreads();                           // win free to overwrite
#pragma unroll
        for (int it = 0; it < 3; ++it) {
            int idx = it * 512 + t;
            if (idx < 1280) {
                int r  = idx / 40;
                int cp = idx - r * 40;
                float4 v = *(const float4*)(xb + (size_t)(cb + r) * 4096 + wsod + cp * 4);
                float* dst = &win[r * WPAD + cp * 4];
                dst[0] = v.x; dst[1] = v.y; dst[2] = v.z; dst[3] = v.w;
            }
        }
        __syncthreads();

#pragma unroll
        for (int tap = 0; tap < 3; ++tap) {
            int s  = tap * 4 + cc;
            int gk = gi + tap - 1;
            bool ok = (gk >= 0) && (gk < 4096);    // conv zero-pad
            int pos = max(gk - wsod, 0);
            float vv[8];
#pragma unroll
            for (int e = 0; e < 8; ++e)
                vv[e] = ok ? win[(q * 8 + e) * WPAD + pos] : 0.f;
            bf16x8 Bv;
#pragma unroll
            for (int e = 0; e < 8; ++e) Bv[e] = (short)f2bf(vv[e]);
            cv = __builtin_amdgcn_mfma_f32_16x16x32_bf16(Ac[s * 64 + l], Bv, cv, 0, 0, 0);
        }
    }

    // ---- exchange conv C-frag (rows q*4+rr = channels) -> convx[ch][i_local] ----
    int ilocal = w * 16 + il;
#pragma unroll
    for (int rr = 0; rr < 4; ++rr) {
        int ch = q * 4 + rr;
        if (ch < 9) convx[ch * 132 + ilocal] = cv[rr];
    }
    __syncthreads();
    float c9[9];
#pragma unroll
    for (int z = 0; z < 9; ++z) c9[z] = convx[z * 132 + ilocal];
    __syncthreads();                               // convx reads before Bl writes

    // ---- per-lane gather params for producer role (i = gi) ----
    int   a_[3];
    float wa_[3], wb_[3];
    bool  okw[3];
#pragma unroll
    for (int k = 0; k < 3; ++k) {
        float offy = c9[2 * k]     + b_off[2 * k];
        float offx = c9[2 * k + 1] + b_off[2 * k + 1];
        offy = fminf(fmaxf(offy, -1024.f), 1024.f);
        offx = fminf(fmaxf(offx, -1024.f), 1024.f);
        float am = c9[6 + k] + b_mod[k];
        float m  = 2.f / (1.f + expf(-am));

        float py = (float)(gi - 1 + k) + offy;
        float y0 = floorf(py);
        int   iy0 = (int)y0;
        float wy1 = py - y0, wy0 = 1.f - wy1;
        float x0f = floorf(offx);
        int   ix0 = (int)x0f;
        float wx1 = offx - x0f, wx0 = 1.f - wx1;

        float sx = (ix0 == 0) ? wx0 : ((ix0 == -1) ? wx1 : 0.f);
        float scal = m * sx;

        float wAv = (iy0 >= 0 && iy0 < 4096)  ? scal * wy0 : 0.f;
        float wBv = (iy0 >= -1 && iy0 < 4095) ? scal * wy1 : 0.f;

        int addr = min(max(iy0, 0), 4094);
        bool eq = (iy0 == addr);
        wa_[k] = eq ? wAv : (iy0 == -1   ? wBv : 0.f);
        wb_[k] = eq ? wBv : (iy0 == 4095 ? wAv : 0.f);
        a_[k]  = addr;
        okw[k] = (bool)__all(addr >= wsod && addr <= wsod + WIN - 2);
    }

    // ---- pass B: producer/consumer GEMM (r12 structure; win from L2) ----
    f32x4 acc[8];
#pragma unroll
    for (int f = 0; f < 8; ++f) acc[f] = (f32x4){0.f, 0.f, 0.f, 0.f};

    // prologue: stage window for cc=0 (L2-warm)
#pragma unroll
    for (int it = 0; it < 3; ++it) {
        int idx = it * 512 + t;
        if (idx < 1280) {
            int r  = idx / 40;
            int cp = idx - r * 40;
            float4 v = *(const float4*)(xb + (size_t)r * 4096 + wsod + cp * 4);
            float* dst = &win[r * WPAD + cp * 4];
            dst[0] = v.x; dst[1] = v.y; dst[2] = v.z; dst[3] = v.w;
        }
    }
    __syncthreads();

    for (int cc = 0; cc < 4; ++cc) {
        int cb = cc * 32;

        // consumer A-frags first (oldest vmcnt; stg stays behind them)
        bf16x8 Areg[3];
#pragma unroll
        for (int k = 0; k < 3; ++k)
            Areg[k] = Ag[(w * 12 + k * 4 + cc) * 64 + l];

        // --- producer: interp own i-frag -> B LDS ---
#pragma unroll
        for (int k = 0; k < 3; ++k) {
            float v[8];
            float wa = wa_[k], wb = wb_[k];
            if (okw[k]) {
                int pos = a_[k] - wsod;
#pragma unroll
                for (int e = 0; e < 8; ++e) {
                    const float* base = &win[(q * 8 + e) * WPAD + pos];
                    v[e] = wa * base[0] + wb * base[1];   // ds_read2_b32
                }
            } else {
                int a = a_[k];
#pragma unroll
                for (int e = 0; e < 8; ++e) {
                    const float* row = xb + (size_t)(cb + q * 8 + e) * 4096;
                    f32x2u p2 = *(const f32x2u*)(row + a);
                    v[e] = wa * p2.x + wb * p2.y;
                }
            }
            bf16x8 Bv;
#pragma unroll
            for (int e = 0; e < 8; ++e) Bv[e] = (short)f2bf(v[e]);
            *(bf16x8*)&Bl[w][k][l * 8] = Bv;
        }

        // --- issue next window's loads (T14; consumer section has no VMEM) ---
        float4 stg[3];
        if (cc < 3) {
            const float* src = xb + (size_t)(cb + 32) * 4096;
#pragma unroll
            for (int it = 0; it < 3; ++it) {
                int idx = it * 512 + t;
                if (idx < 1280) {
                    int r  = idx / 40;
                    int cp = idx - r * 40;
                    stg[it] = *(const float4*)(src + (size_t)r * 4096 + wsod + cp * 4);
                }
            }
        }
        __syncthreads();                            // Bl ready; win reads done

        // --- consumer: pure LDS + MFMA ---
        __builtin_amdgcn_s_setprio(1);
#pragma unroll
        for (int f = 0; f < 8; ++f) {
#pragma unroll
            for (int k = 0; k < 3; ++k) {
                bf16x8 Bv = *(const bf16x8*)&Bl[f][k][l * 8];
                acc[f] = __builtin_amdgcn_mfma_f32_16x16x32_bf16(Areg[k], Bv, acc[f], 0, 0, 0);
            }
        }
        __builtin_amdgcn_s_setprio(0);

        // --- write staged window; barrier closes phase (orders Bl reuse too) ---
        if (cc < 3) {
#pragma unroll
            for (int it = 0; it < 3; ++it) {
                int idx = it * 512 + t;
                if (idx < 1280) {
                    int r  = idx / 40;
                    int cp = idx - r * 40;
                    float* dst = &win[r * WPAD + cp * 4];
                    dst[0] = stg[it].x; dst[1] = stg[it].y;
                    dst[2] = stg[it].z; dst[3] = stg[it].w;
                }
            }
            __syncthreads();
        }
    }

    // C layout: col = lane&15, row = (lane>>4)*4 + reg. Wave w -> o rows w*16..+15.
    int r0 = q * 4;
#pragma unroll
    for (int f = 0; f < 8; ++f) {
#pragma unroll
        for (int r = 0; r < 4; ++r) {
            int o = w * 16 + r0 + r;
            out[((size_t)(b * 128 + o)) * 4096 + i0t + f * 16 + il] = acc[f][r];
        }
    }
}

extern "C" void kernel_launch(void* const* d_in, const int* in_sizes, int n_in,
                              void* d_out, int out_size, void* d_ws, size_t ws_size,
                              hipStream_t stream) {
    const float* x     = (const float*)d_in[0];
    const float* w_off = (const float*)d_in[1];
    const float* b_off = (const float*)d_in[2];
    const float* w_mod = (const float*)d_in[3];
    const float* b_mod = (const float*)d_in[4];
    const float* w_reg = (const float*)d_in[5];
    float* out = (float*)d_out;

    char* ws = (char*)d_ws;
    unsigned short* WrA = (unsigned short*)(ws);
    unsigned short* WcA = (unsigned short*)(ws + 98304);

    k_wra<<<216, 256, 0, stream>>>(w_reg, w_off, w_mod, WrA, WcA);
    k_all<<<dim3(32, 32), 512, 0, stream>>>(WrA, WcA, x, b_off, b_mod, out);
}

// Round 14
// 67.147 us; speedup vs baseline: 1.4509x; 1.4509x over previous
//
#include <hip/hip_runtime.h>
#include <hip/hip_bf16.h>
#include <math.h>

// Shapes: B=32, C=128, O=128, K=3, L=4096, W=1, PAD=1, DIL=1
// out[b,o,i] = sum_kc Wr[kc,o] * G[b,kc,i],  kc = k*128+c (K=384)
// G[b,kc,i] = wae[b,k,i]*x[b,c,addr] + wbe[b,k,i]*x[b,c,addr+1]
//
// r14 = r12 split (best-known pieces) + T3/T4 barrier surgery in k_fused:
//   raw s_barrier with lgkmcnt-only waits -> staging global loads stay in
//   flight across barrier #1 and drain under/after the MFMA cluster
//   (the __syncthreads vmcnt(0) drain was the exposed-latency culprit).
//
// ws layout (bytes):
//   WrA @ 0       : bf16 A-frags, 8 m x 12 s x 64 lanes x 16B = 98304
//   wT  @ 98304   : float[128*32] transposed conv weights, wT[c*32+ch*3+tap]
//   addr2 @ 131072: int[32*3*4096]
//   wae @ 1703936 : float[32*3*4096]
//   wbe @ 3276800 : float[32*3*4096]

typedef __attribute__((ext_vector_type(8))) short bf16x8;
typedef __attribute__((ext_vector_type(4))) float f32x4;
typedef float f32x2u __attribute__((ext_vector_type(2), aligned(4)));

#define WIN 160
#define WPAD 161

static __device__ inline unsigned short f2bf(float f) {
    __hip_bfloat16 h = __float2bfloat16(f);
    union { __hip_bfloat16 b; unsigned short u; } cv;
    cv.b = h;
    return cv.u;
}

// ---------- kernel 0: pack WrA (A-frags) + wT (transposed conv weights) ----------
// A-frag (m,s), lane l, elem e:  A[o = m*16+(l&15)][kc = s*32+(l>>4)*8+e]
__global__ __launch_bounds__(256) void k_wra(const float* __restrict__ w_reg,
                                             const float* __restrict__ w_off,
                                             const float* __restrict__ w_mod,
                                             unsigned short* __restrict__ WrA,
                                             float* __restrict__ wT) {
    int t = blockIdx.x * 256 + threadIdx.x;
    if (t < 8 * 12 * 64 * 8) {
        int e  = t & 7;
        int l  = (t >> 3) & 63;
        int ms = t >> 9;              // m*12 + s
        int m  = ms / 12;
        int s  = ms - m * 12;
        int o  = m * 16 + (l & 15);
        int kc = s * 32 + ((l >> 4) & 3) * 8 + e;
        int tap = kc >> 7;
        int c   = kc & 127;
        WrA[t] = f2bf(w_reg[(o * 128 + c) * 3 + tap]);
    } else if (t < 8 * 12 * 64 * 8 + 128 * 27) {
        int u = t - 8 * 12 * 64 * 8;
        int c = u / 27, r = u - c * 27;
        int ch = r / 3, tap = r - ch * 3;
        wT[c * 32 + r] = (ch < 6) ? w_off[(ch * 128 + c) * 3 + tap]
                                  : w_mod[((ch - 6) * 128 + c) * 3 + tap];
    }
}

// ---------- kernel 1: offset/mask conv, 8 waves x 16 channels (r9 exact) ----------
// grid (32, 32): 128-i tiles, lane owns i,i+1. Wave wv sums c in [16wv,16wv+16).
__global__ __launch_bounds__(512) void k_prep(const float* __restrict__ x,
                                              const float* __restrict__ wT,
                                              const float* __restrict__ b_off,
                                              const float* __restrict__ b_mod,
                                              int* __restrict__ addr2,
                                              float* __restrict__ wae,
                                              float* __restrict__ wbe) {
    __shared__ float red[7 * 64 * 19];            // 34 KB, stride 19 (odd)
    int t = threadIdx.x;
    int lane = t & 63;
    int wv = t >> 6;                              // 0..7
    int b = blockIdx.y;
    int i = blockIdx.x * 128 + lane * 2;          // lane covers i, i+1

    int c0 = __builtin_amdgcn_readfirstlane(wv) * 16;

    float acc[18];
#pragma unroll
    for (int z = 0; z < 18; ++z) acc[z] = 0.f;

    const float* xr = x + (size_t)b * 524288 + (size_t)c0 * 4096;
    const float* wbase = wT + c0 * 32;
#pragma unroll 2
    for (int c = 0; c < 16; ++c) {
        const float* row = xr + (size_t)c * 4096;
        f32x2u v = *(const f32x2u*)(row + i);
        float lm = row[max(i - 1, 0)];            // unconditional, no divergence
        float rp = row[min(i + 2, 4095)];
        float left  = (i > 0)        ? lm : 0.f;
        float right = (i + 2 < 4096) ? rp : 0.f;
        const float* wrow = wbase + c * 32;       // wave-uniform -> s_load
#pragma unroll
        for (int ch = 0; ch < 9; ++ch) {
            float w0 = wrow[ch * 3 + 0];
            float w1 = wrow[ch * 3 + 1];
            float w2 = wrow[ch * 3 + 2];
            acc[ch * 2 + 0] += left * w0 + v.x * w1 + v.y  * w2;
            acc[ch * 2 + 1] += v.x  * w0 + v.y * w1 + right * w2;
        }
    }

    if (wv > 0) {
        float* r = &red[((wv - 1) * 64 + lane) * 19];
#pragma unroll
        for (int z = 0; z < 18; ++z) r[z] = acc[z];
    }
    __syncthreads();
    if (wv != 0) return;

#pragma unroll
    for (int p = 0; p < 7; ++p) {
        const float* r = &red[(p * 64 + lane) * 19];
#pragma unroll
        for (int z = 0; z < 18; ++z) acc[z] += r[z];
    }

#pragma unroll
    for (int k = 0; k < 3; ++k) {
        int   av[2];
        float wav[2], wbv[2];
#pragma unroll
        for (int ii = 0; ii < 2; ++ii) {
            float offy = acc[(2 * k) * 2 + ii]     + b_off[2 * k];
            float offx = acc[(2 * k + 1) * 2 + ii] + b_off[2 * k + 1];
            offy = fminf(fmaxf(offy, -1024.f), 1024.f);
            offx = fminf(fmaxf(offx, -1024.f), 1024.f);
            float am = acc[(6 + k) * 2 + ii] + b_mod[k];
            float m  = 2.f / (1.f + expf(-am));

            float py = (float)(i + ii - 1 + k) + offy;
            float y0 = floorf(py);
            int   iy0 = (int)y0;
            float wy1 = py - y0, wy0 = 1.f - wy1;
            float x0f = floorf(offx);
            int   ix0 = (int)x0f;
            float wx1 = offx - x0f, wx0 = 1.f - wx1;

            float sx = (ix0 == 0) ? wx0 : ((ix0 == -1) ? wx1 : 0.f);
            float scal = m * sx;

            float wAv = (iy0 >= 0 && iy0 < 4096)  ? scal * wy0 : 0.f;
            float wBv = (iy0 >= -1 && iy0 < 4095) ? scal * wy1 : 0.f;

            int addr = min(max(iy0, 0), 4094);
            bool eq = (iy0 == addr);
            wav[ii] = eq ? wAv : (iy0 == -1   ? wBv : 0.f);
            wbv[ii] = eq ? wBv : (iy0 == 4095 ? wAv : 0.f);
            av[ii] = addr;
        }
        int j = (b * 3 + k) * 4096 + i;
        *(int2*)(addr2 + j)  = make_int2(av[0], av[1]);
        *(f32x2u*)(wae + j)  = (f32x2u){wav[0], wav[1]};
        *(f32x2u*)(wbe + j)  = (f32x2u){wbv[0], wbv[1]};
    }
}

// ---------- kernel 2: fused gather + MFMA GEMM, raw-barrier phase loop ----------
// grid (32 i-tiles, 32 b), 512 threads = 8 waves. Block: 128 i x 128 o.
// Producer: wave w interps i-frag w -> Bl[w][k] (single-buffered).
// Consumer: wave w = m-frag w, A-frags in registers.
// Barriers carry ONLY lgkmcnt(0); staging vmcnt drains under/after MFMA.
__global__ __launch_bounds__(512) void k_fused(const unsigned short* __restrict__ WrA,
                                               const float* __restrict__ x,
                                               const int* __restrict__ addr2,
                                               const float* __restrict__ wae,
                                               const float* __restrict__ wbe,
                                               float* __restrict__ out) {
    __shared__ float win[32 * WPAD];               // 20.6 KB
    __shared__ short Bl[8][3][512];                // 24 KB single buffer
    int t = threadIdx.x;
    int l = t & 63;
    int w = t >> 6;                                // 0..7
    int b  = blockIdx.y;
    int ib = blockIdx.x;
    int q = l >> 4;
    int il = l & 15;
    int i0t = ib * 128;
    int i0p = i0t + w * 16 + il;                   // producer's i
    int wsod = i0t - 16;
    if (wsod > 4096 - WIN) wsod = 4096 - WIN;
    if (wsod < 0) wsod = 0;
    const float* xb = x + (size_t)b * 524288;
    const bf16x8* Ag = (const bf16x8*)WrA;

    // producer gather params (own i-frag) + wave-uniform in-window flags
    int   a_[3];
    float wa_[3], wb_[3];
    bool  okw[3];
#pragma unroll
    for (int k = 0; k < 3; ++k) {
        int j = (b * 3 + k) * 4096 + i0p;
        int a = addr2[j];
        a_[k]  = a;
        wa_[k] = wae[j];
        wb_[k] = wbe[j];
        okw[k] = (bool)__all(a >= wsod && a <= wsod + WIN - 2);
    }

    f32x4 acc[8];
#pragma unroll
    for (int f = 0; f < 8; ++f) acc[f] = (f32x4){0.f, 0.f, 0.f, 0.f};

    // prologue: stage window for cc=0 (full sync is fine once)
#pragma unroll
    for (int it = 0; it < 3; ++it) {
        int idx = it * 512 + t;
        if (idx < 1280) {
            int r  = idx / 40;
            int cp = idx - r * 40;
            float4 v = *(const float4*)(xb + (size_t)r * 4096 + wsod + cp * 4);
            float* dst = &win[r * WPAD + cp * 4];
            dst[0] = v.x; dst[1] = v.y; dst[2] = v.z; dst[3] = v.w;
        }
    }
    __syncthreads();

    for (int cc = 0; cc < 4; ++cc) {
        int cb = cc * 32;

        // consumer A-frags first (oldest VMEM; stg loads queue behind them,
        // so the compiler's Areg wait is vmcnt(3), leaving stg in flight)
        bf16x8 Areg[3];
#pragma unroll
        for (int k = 0; k < 3; ++k)
            Areg[k] = Ag[(w * 12 + k * 4 + cc) * 64 + l];

        // --- producer: interp own i-frag -> B LDS ---
#pragma unroll
        for (int k = 0; k < 3; ++k) {
            float v[8];
            float wa = wa_[k], wb = wb_[k];
            if (okw[k]) {
                int pos = a_[k] - wsod;
#pragma unroll
                for (int e = 0; e < 8; ++e) {
                    const float* base = &win[(q * 8 + e) * WPAD + pos];
                    v[e] = wa * base[0] + wb * base[1];   // ds_read2_b32
                }
            } else {
                int a = a_[k];
#pragma unroll
                for (int e = 0; e < 8; ++e) {
                    const float* row = xb + (size_t)(cb + q * 8 + e) * 4096;
                    f32x2u p2 = *(const f32x2u*)(row + a);
                    v[e] = wa * p2.x + wb * p2.y;
                }
            }
            bf16x8 Bv;
#pragma unroll
            for (int e = 0; e < 8; ++e) Bv[e] = (short)f2bf(v[e]);
            *(bf16x8*)&Bl[w][k][l * 8] = Bv;
        }

        // --- issue next window's loads; they stay in flight across barrier #1 ---
        float4 stg[3];
        if (cc < 3) {
            const float* src = xb + (size_t)(cb + 32) * 4096;
#pragma unroll
            for (int it = 0; it < 3; ++it) {
                int idx = it * 512 + t;
                if (idx < 1280) {
                    int r  = idx / 40;
                    int cp = idx - r * 40;
                    stg[it] = *(const float4*)(src + (size_t)r * 4096 + wsod + cp * 4);
                }
            }
        }

        // barrier #1: Bl writes + win reads complete (LDS only — NO vmcnt drain)
        asm volatile("s_waitcnt lgkmcnt(0)" ::: "memory");
        __builtin_amdgcn_sched_barrier(0);
        __builtin_amdgcn_s_barrier();

        // --- consumer: pure LDS + MFMA (stg HBM latency hides under this) ---
        __builtin_amdgcn_s_setprio(1);
#pragma unroll
        for (int f = 0; f < 8; ++f) {
#pragma unroll
            for (int k = 0; k < 3; ++k) {
                bf16x8 Bv = *(const bf16x8*)&Bl[f][k][l * 8];
                acc[f] = __builtin_amdgcn_mfma_f32_16x16x32_bf16(Areg[k], Bv, acc[f], 0, 0, 0);
            }
        }
        __builtin_amdgcn_s_setprio(0);

        // --- write staged window (compiler waits stg's vmcnt here, post-MFMA) ---
        if (cc < 3) {
#pragma unroll
            for (int it = 0; it < 3; ++it) {
                int idx = it * 512 + t;
                if (idx < 1280) {
                    int r  = idx / 40;
                    int cp = idx - r * 40;
                    float* dst = &win[r * WPAD + cp * 4];
                    dst[0] = stg[it].x; dst[1] = stg[it].y;
                    dst[2] = stg[it].z; dst[3] = stg[it].w;
                }
            }
            // barrier #2: win writes visible + all Bl reads done (LDS only)
            asm volatile("s_waitcnt lgkmcnt(0)" ::: "memory");
            __builtin_amdgcn_sched_barrier(0);
            __builtin_amdgcn_s_barrier();
        }
    }

    // C layout: col = lane&15, row = (lane>>4)*4 + reg. Wave w -> o rows w*16..+15.
    int r0 = q * 4;
#pragma unroll
    for (int f = 0; f < 8; ++f) {
#pragma unroll
        for (int r = 0; r < 4; ++r) {
            int o = w * 16 + r0 + r;
            out[((size_t)(b * 128 + o)) * 4096 + i0t + f * 16 + il] = acc[f][r];
        }
    }
}

extern "C" void kernel_launch(void* const* d_in, const int* in_sizes, int n_in,
                              void* d_out, int out_size, void* d_ws, size_t ws_size,
                              hipStream_t stream) {
    const float* x     = (const float*)d_in[0];
    const float* w_off = (const float*)d_in[1];
    const float* b_off = (const float*)d_in[2];
    const float* w_mod = (const float*)d_in[3];
    const float* b_mod = (const float*)d_in[4];
    const float* w_reg = (const float*)d_in[5];
    float* out = (float*)d_out;

    char* ws = (char*)d_ws;
    unsigned short* WrA = (unsigned short*)(ws);
    float* wT    = (float*)(ws + 98304);
    int*   addr2 = (int*)  (ws + 131072);
    float* wae   = (float*)(ws + 1703936);
    float* wbe   = (float*)(ws + 3276800);

    k_wra<<<206, 256, 0, stream>>>(w_reg, w_off, w_mod, WrA, wT);
    k_prep<<<dim3(32, 32), 512, 0, stream>>>(x, wT, b_off, b_mod,
                                             addr2, wae, wbe);
    k_fused<<<dim3(32, 32), 512, 0, stream>>>(WrA, x, addr2, wae, wbe, out);
}